// Round 2
// baseline (799.850 us; speedup 1.0000x reference)
//
#include <hip/hip_runtime.h>

#define BATCH 512
#define TT 256
#define HH 256
#define HOR 22

typedef __attribute__((ext_vector_type(8))) short short8x;   // 8 bf16 (4 VGPRs)
typedef __attribute__((ext_vector_type(4))) float f32x4;

__device__ __forceinline__ float rcp_(float x) { return __builtin_amdgcn_rcpf(x); }
__device__ __forceinline__ float sigmoidf_(float x) { return rcp_(1.0f + __expf(-x)); }
__device__ __forceinline__ float tanhf_(float x) {
    float e = __expf(-2.0f * fabsf(x));
    float t = (1.0f - e) * rcp_(1.0f + e);
    return copysignf(t, x);
}
__device__ __forceinline__ unsigned f2bf_rne(float f) {
    unsigned u = __float_as_uint(f);
    unsigned lsb = (u >> 16) & 1u;
    return (u + 0x7FFFu + lsb) >> 16;
}

// ---------------- prep: U matrices -> MFMA B-fragment layout ----------------
// B-frag for (gate, col-tile ct, K-tile kt): lane holds 8 bf16 of
// U[k][col] with col = ct*16 + (lane&15), k = kt*32 + (lane>>4)*8 + j.
// One thread per (gate, ct, kt, lane) writes its 16B fragment.
__global__ __launch_bounds__(256) void prep_kernel(const float* __restrict__ Uz,
                                                   const float* __restrict__ Ur,
                                                   const float* __restrict__ Uh,
                                                   unsigned short* __restrict__ UB) {
    int tid = blockIdx.x * 256 + threadIdx.x;   // 0 .. 24575
    int gate = tid >> 13;                        // 3 gates x 8192
    int rem  = tid & 8191;
    int ct   = rem >> 9;                         // 0..15
    int kt   = (rem >> 6) & 7;                   // 0..7
    int lane = rem & 63;
    int col  = ct * 16 + (lane & 15);
    int kbase = kt * 32 + (lane >> 4) * 8;
    const float* src = (gate == 0) ? Uz : (gate == 1) ? Ur : Uh;
    unsigned v[4];
#pragma unroll
    for (int jp = 0; jp < 4; ++jp) {
        unsigned lo = f2bf_rne(src[(kbase + 2 * jp)     * HH + col]);
        unsigned hi = f2bf_rne(src[(kbase + 2 * jp + 1) * HH + col]);
        v[jp] = lo | (hi << 16);
    }
    ((uint4*)UB)[tid] = make_uint4(v[0], v[1], v[2], v[3]);
}

// ---------------- persistent GRU: 1 WG = 16 batch rows, 8 waves, MFMA ----------------
// Wave w owns output cols [32w, 32w+32) (col-tiles 2w, 2w+1) for all 3 gates:
// 48 B-frags = 192 regs -> AGPRs (MFMA reads AGPR natively; no accvgpr moves).
// Arch working set kept ~60 regs: params table in LDS, imm-offset addressing.
//
// LDS map (bytes):
//   0     : hA buf0   (8 KB)  h in A-frag layout   [epilogue: hsF 16x256 f32]
//   8192  : hA buf1   (8 KB)
//   16384 : rhA       (8 KB)  r*h in A-frag layout [epilogue: hid 16x256 f32]
//   24576 : params    (8 KB)  8 x 256 f32
//   32768 : xs        (16 KB) 16 x 256 f32         [epilogue: sigL 16 f32]
__global__ __launch_bounds__(512) __attribute__((amdgpu_waves_per_eu(2, 2))) void gru_kernel(
    const float* __restrict__ x,
    const float* __restrict__ Wzw, const float* __restrict__ Wzb, const float* __restrict__ Uzb,
    const float* __restrict__ Wrw, const float* __restrict__ Wrb, const float* __restrict__ Urb,
    const float* __restrict__ Whw, const float* __restrict__ Whb, const float* __restrict__ Uhb,
    const float* __restrict__ Wgw, const float* __restrict__ Wgb,
    const float* __restrict__ om_raw, const float* __restrict__ al_raw,
    const float* __restrict__ be_raw, const float* __restrict__ gam,
    const float* __restrict__ fc1w, const float* __restrict__ fc1b,
    const float* __restrict__ fc2w, const float* __restrict__ fc2b,
    const unsigned short* __restrict__ UB,
    float* __restrict__ out) {

    __shared__ __align__(16) char lds[49152];

    const int t    = threadIdx.x;
    const int w    = t >> 6;        // wave 0..7
    const int lane = t & 63;
    const int n    = lane & 15;     // col within tile
    const int g    = lane >> 4;     // row group / k group
    const int b0   = blockIdx.x * 16;

    // ---- weights -> registers (regalloc places them in AGPRs) ----
    short8x Wz[2][8], Wr[2][8], Wh[2][8];
    {
        const short8x* ub = (const short8x*)UB;
#pragma unroll
        for (int tile = 0; tile < 2; ++tile) {
            const int ct = 2 * w + tile;
#pragma unroll
            for (int kt = 0; kt < 8; ++kt) {
                Wz[tile][kt] = ub[((0 * 16 + ct) * 8 + kt) * 64 + lane];
                Wr[tile][kt] = ub[((1 * 16 + ct) * 8 + kt) * 64 + lane];
                Wh[tile][kt] = ub[((2 * 16 + ct) * 8 + kt) * 64 + lane];
            }
        }
    }

    // ---- stage x rows: xs[r][tp] ----
    {
        float* xsF = (float*)(lds + 32768);
#pragma unroll
        for (int it = 0; it < 8; ++it) {
            int i = t + it * 512;               // 0..4095
            int r = i >> 8, tp = i & 255;
            xsF[r * 256 + tp] = x[(b0 + r) * TT + tp];
        }
    }
    // ---- per-column param table ----
    {
        float* pF = (float*)(lds + 24576);
#pragma unroll
        for (int it = 0; it < 4; ++it) {
            int i = t + it * 512;               // 0..2047
            int p = i >> 8, c = i & 255;
            float v;
            switch (p) {
                case 0: v = Wzw[c]; break;
                case 1: v = Wzb[c] + Uzb[c]; break;
                case 2: v = Wrw[c]; break;
                case 3: v = Wrb[c] + Urb[c]; break;
                case 4: v = Whw[c]; break;
                case 5: v = Whb[c] + Uhb[c]; break;
                case 6: v = Wgw[c]; break;
                default: v = Wgb[c]; break;
            }
            pF[i] = v;
        }
    }
    // ---- zero h buffer 0 ----
    {
        unsigned* z0 = (unsigned*)lds;
#pragma unroll
        for (int it = 0; it < 4; ++it) z0[t + it * 512] = 0;
    }

    // scalar params (uniform -> SGPRs)
    const float omega = log1pf(__expf(om_raw[0])) + 1e-6f;
    const float aco   = sigmoidf_(al_raw[0]);
    const float bco   = sigmoidf_(be_raw[0]) * (1.0f - aco * 0.99f);
    const float gma   = gam[0];

    // address bases (imm-offset addressing: one VGPR per stream)
    const int rdH   = lane * 16;                              // + hbase + kt*1024
    const int rdR   = 16384 + lane * 16;                      // + kt*1024
    const int wrPat = g * 64 + (n >> 3) * 256 + (n & 7) * 2;  // + tile*512 + i*16
    const int pvOff = 24576 + (w * 32 + n) * 4;               // + p*1024 + tile*64
    const int xvOff = 32768 + g * 4096;                       // + i*1024 + tt*4

    f32x4 h_own[2];
    h_own[0] = (f32x4){0.f, 0.f, 0.f, 0.f};
    h_own[1] = (f32x4){0.f, 0.f, 0.f, 0.f};
    float sg[4] = {1e-6f, 1e-6f, 1e-6f, 1e-6f};

    __syncthreads();

    int hbase = 0;
    for (int tt = 0; tt < TT; ++tt) {
        // current x for this lane's 4 rows
        float xc[4];
#pragma unroll
        for (int i = 0; i < 4; ++i)
            xc[i] = *(const float*)(lds + xvOff + i * 1024 + tt * 4);

        // ---- phase A: Cz, Cr = h @ Uz, h @ Ur ----
        f32x4 Cz[2], Cr[2];
#pragma unroll
        for (int tile = 0; tile < 2; ++tile) {
            Cz[tile] = (f32x4){0.f, 0.f, 0.f, 0.f};
            Cr[tile] = (f32x4){0.f, 0.f, 0.f, 0.f};
        }
#pragma unroll
        for (int kt = 0; kt < 8; ++kt) {
            short8x ah = *(const short8x*)(lds + hbase + rdH + kt * 1024);
            Cz[0] = __builtin_amdgcn_mfma_f32_16x16x32_bf16(ah, Wz[0][kt], Cz[0], 0, 0, 0);
            Cz[1] = __builtin_amdgcn_mfma_f32_16x16x32_bf16(ah, Wz[1][kt], Cz[1], 0, 0, 0);
            Cr[0] = __builtin_amdgcn_mfma_f32_16x16x32_bf16(ah, Wr[0][kt], Cr[0], 0, 0, 0);
            Cr[1] = __builtin_amdgcn_mfma_f32_16x16x32_bf16(ah, Wr[1][kt], Cr[1], 0, 0, 0);
        }
        // elementwise z, r; write r*h (bf16, A-frag layout)
        f32x4 zst[2];
#pragma unroll
        for (int tile = 0; tile < 2; ++tile) {
            const float wzp = *(const float*)(lds + pvOff + 0 * 1024 + tile * 64);
            const float bzp = *(const float*)(lds + pvOff + 1 * 1024 + tile * 64);
            const float wrp = *(const float*)(lds + pvOff + 2 * 1024 + tile * 64);
            const float brp = *(const float*)(lds + pvOff + 3 * 1024 + tile * 64);
#pragma unroll
            for (int i = 0; i < 4; ++i) {
                float zv = sigmoidf_(Cz[tile][i] + xc[i] * wzp + bzp);
                float rv = sigmoidf_(Cr[tile][i] + xc[i] * wrp + brp);
                float rh = rv * h_own[tile][i];
                *(unsigned short*)(lds + 16384 + wrPat + tile * 512 + i * 16) =
                    (unsigned short)f2bf_rne(rh);
                zst[tile][i] = zv;
            }
        }
        __syncthreads();

        // ---- phase B: Ch = (r*h) @ Uh ----
        f32x4 Ch[2];
        Ch[0] = (f32x4){0.f, 0.f, 0.f, 0.f};
        Ch[1] = (f32x4){0.f, 0.f, 0.f, 0.f};
#pragma unroll
        for (int kt = 0; kt < 8; ++kt) {
            short8x ar = *(const short8x*)(lds + rdR + kt * 1024);
            Ch[0] = __builtin_amdgcn_mfma_f32_16x16x32_bf16(ar, Wh[0][kt], Ch[0], 0, 0, 0);
            Ch[1] = __builtin_amdgcn_mfma_f32_16x16x32_bf16(ar, Wh[1][kt], Ch[1], 0, 0, 0);
        }
        // garch recurrence per owned row
        float gv[4];
#pragma unroll
        for (int i = 0; i < 4; ++i) {
            float xp = *(const float*)(lds + xvOff + i * 1024 + tt * 4 - 4);
            float ep = (tt == 0) ? 1e-6f : xp * xp;
            gv[i] = omega + aco * ep + bco * sg[i];
            sg[i] = gv[i];
        }
        // elementwise h_new; write h (bf16, A-frag layout, other buffer)
#pragma unroll
        for (int tile = 0; tile < 2; ++tile) {
            const float whp = *(const float*)(lds + pvOff + 4 * 1024 + tile * 64);
            const float bhp = *(const float*)(lds + pvOff + 5 * 1024 + tile * 64);
            const float wgp = *(const float*)(lds + pvOff + 6 * 1024 + tile * 64);
            const float bgp = *(const float*)(lds + pvOff + 7 * 1024 + tile * 64);
#pragma unroll
            for (int i = 0; i < 4; ++i) {
                float htld = tanhf_(Ch[tile][i] + xc[i] * whp + bhp);
                float zv   = zst[tile][i];
                float hh   = (1.f - zv) * htld + zv * h_own[tile][i];
                float hn   = tanhf_(hh + gma * (gv[i] * wgp + bgp));
                h_own[tile][i] = hn;
                *(unsigned short*)(lds + (hbase ^ 8192) + wrPat + tile * 512 + i * 16) =
                    (unsigned short)f2bf_rne(hn);
            }
        }
        hbase ^= 8192;
        __syncthreads();
    }

    // ---- stash exact fp32 h (overlay hA bufs) + sigma_sq ----
    {
        float* hsF = (float*)lds;
#pragma unroll
        for (int tile = 0; tile < 2; ++tile)
#pragma unroll
            for (int i = 0; i < 4; ++i) {
                int r = g * 4 + i, c = (2 * w + tile) * 16 + n;
                hsF[r * 256 + c] = h_own[tile][i];
            }
        if (w == 0 && n == 0) {
            float* sigL = (float*)(lds + 32768);
#pragma unroll
            for (int i = 0; i < 4; ++i) sigL[g * 4 + i] = sg[i];
        }
    }
    __syncthreads();

    // ---- head: hid = relu(h @ fc1 + b1) ----
    {
        const int j = t & 255, bg2 = t >> 8;   // bg2: 0..1 -> rows bg2*8 .. +7
        const float* hsF = (const float*)lds;
        float acc[8];
#pragma unroll
        for (int r2 = 0; r2 < 8; ++r2) acc[r2] = 0.f;
        for (int k = 0; k < HH; ++k) {
            float wv = fc1w[k * HH + j];
#pragma unroll
            for (int r2 = 0; r2 < 8; ++r2)
                acc[r2] += hsF[(bg2 * 8 + r2) * 256 + k] * wv;
        }
        float* hid = (float*)(lds + 16384);
        const float b1 = fc1b[j];
#pragma unroll
        for (int r2 = 0; r2 < 8; ++r2)
            hid[(bg2 * 8 + r2) * 256 + j] = fmaxf(acc[r2] + b1, 0.f);
    }
    __syncthreads();

    // ---- head: nn_scale / vol ----
    if (t < 16 * HOR) {
        const int b = t / HOR, c = t % HOR;
        const float* hid = (const float*)(lds + 16384);
        float acc = fc2b[c];
        for (int k = 0; k < HH; ++k) acc += hid[b * 256 + k] * fc2w[k * HOR + c];
        const float sp = log1pf(__expf(acc));
        const float sgv = ((const float*)(lds + 32768))[b];
        const float vb = sqrtf(sgv + 1e-8f);
        float vol = vb * (1.0f + sp);
        vol = fminf(fmaxf(vol, 0.01f), 10.0f);
        out[(b0 + b) * HOR + c] = vol;
    }
    if (t < 16) out[BATCH * HOR + b0 + t] = ((const float*)(lds + 32768))[t];
}

extern "C" void kernel_launch(void* const* d_in, const int* in_sizes, int n_in,
                              void* d_out, int out_size, void* d_ws, size_t ws_size,
                              hipStream_t stream) {
    const float* x    = (const float*)d_in[0];
    const float* Wzw  = (const float*)d_in[1];
    const float* Wzb  = (const float*)d_in[2];
    const float* Uzw  = (const float*)d_in[3];
    const float* Uzb  = (const float*)d_in[4];
    const float* Wrw  = (const float*)d_in[5];
    const float* Wrb  = (const float*)d_in[6];
    const float* Urw  = (const float*)d_in[7];
    const float* Urb  = (const float*)d_in[8];
    const float* Whw  = (const float*)d_in[9];
    const float* Whb  = (const float*)d_in[10];
    const float* Uhw  = (const float*)d_in[11];
    const float* Uhb  = (const float*)d_in[12];
    const float* Wgw  = (const float*)d_in[13];
    const float* Wgb  = (const float*)d_in[14];
    const float* om   = (const float*)d_in[15];
    const float* al   = (const float*)d_in[16];
    const float* be   = (const float*)d_in[17];
    const float* ga   = (const float*)d_in[18];
    const float* fc1w = (const float*)d_in[19];
    const float* fc1b = (const float*)d_in[20];
    const float* fc2w = (const float*)d_in[21];
    const float* fc2b = (const float*)d_in[22];

    unsigned short* UB = (unsigned short*)d_ws;   // 24576 x 16B fragments = 384 KB

    prep_kernel<<<96, 256, 0, stream>>>(Uzw, Urw, Uhw, UB);
    gru_kernel<<<32, 512, 0, stream>>>(x, Wzw, Wzb, Uzb, Wrw, Wrb, Urb, Whw, Whb, Uhb,
                                       Wgw, Wgb, om, al, be, ga, fc1w, fc1b, fc2w, fc2b,
                                       UB, (float*)d_out);
}